// Round 6
// baseline (1164.275 us; speedup 1.0000x reference)
//
#include <hip/hip_runtime.h>
#include <hip/hip_bf16.h>
#include <math.h>

#define TT 4096
#define DIM 512
#define FFN 2048
#define NVOCAB 32000

typedef __attribute__((ext_vector_type(8))) short short8_t;
typedef __attribute__((ext_vector_type(4))) float f32x4;

__device__ __forceinline__ float gelu_f(float x) {
    float x3 = x * x * x;
    float u = 0.7978845608028654f * (x + 0.044715f * x3);
    return 0.5f * x * (1.0f + tanhf(u));
}

__device__ __forceinline__ unsigned short f2bf_rn(float f) {
    unsigned u = __float_as_uint(f);
    u += 0x7FFFu + ((u >> 16) & 1u);
    return (unsigned short)(u >> 16);
}

// -------------------- embedding gather + flag init --------------------
__global__ __launch_bounds__(128) void gather_kernel(const int* __restrict__ x,
                                                     const float* __restrict__ emb,
                                                     float* __restrict__ h,
                                                     int* __restrict__ flags) {
    int t = blockIdx.x;
    int idx = x[t];
    const float4 v = *(const float4*)&emb[(size_t)idx * DIM + threadIdx.x * 4];
    *(float4*)&h[(size_t)t * DIM + threadIdx.x * 4] = v;
    if (threadIdx.x == 0) flags[t] = 1;
}

// -------------------- fp32 -> bf16 hi/lo split (flat) --------------------
__global__ __launch_bounds__(256) void cvt_hilo(const float* __restrict__ src,
                                                short* __restrict__ hi,
                                                short* __restrict__ lo, int n4) {
    int i = blockIdx.x * 256 + threadIdx.x;
    if (i >= n4) return;
    float4 v = *(const float4*)&src[(size_t)i * 4];
    float f[4] = {v.x, v.y, v.z, v.w};
    short4 hv, lv;
    short* hp = &hv.x;
    short* lp = &lv.x;
#pragma unroll
    for (int j = 0; j < 4; ++j) {
        unsigned short hb = f2bf_rn(f[j]);
        float hf = __uint_as_float((unsigned)hb << 16);
        unsigned short lb = f2bf_rn(f[j] - hf);
        hp[j] = (short)hb;
        lp[j] = (short)lb;
    }
    *(short4*)&hi[(size_t)i * 4] = hv;
    *(short4*)&lo[(size_t)i * 4] = lv;
}

// -------------------- fp32 W (K,N) -> bf16 hi/lo transposed (N,K) --------------------
__global__ __launch_bounds__(256) void cvt_w_t(const float* __restrict__ W,
                                               short* __restrict__ hiT,
                                               short* __restrict__ loT,
                                               int K, int N) {
    __shared__ short hs[32][36];
    __shared__ short ls[32][36];
    const int n0 = blockIdx.x * 32, k0 = blockIdx.y * 32;
    const int r = threadIdx.x >> 3, c4 = (threadIdx.x & 7) << 2;
    float4 v = *(const float4*)&W[(size_t)(k0 + r) * N + n0 + c4];
    float f[4] = {v.x, v.y, v.z, v.w};
#pragma unroll
    for (int j = 0; j < 4; ++j) {
        unsigned short hb = f2bf_rn(f[j]);
        float hf = __uint_as_float((unsigned)hb << 16);
        unsigned short lb = f2bf_rn(f[j] - hf);
        hs[r][c4 + j] = (short)hb;
        ls[r][c4 + j] = (short)lb;
    }
    __syncthreads();
    const int nr = threadIdx.x >> 3, kc4 = (threadIdx.x & 7) << 2;
    short4 hv, lv;
    short* hp = &hv.x;
    short* lp = &lv.x;
#pragma unroll
    for (int j = 0; j < 4; ++j) {
        hp[j] = hs[kc4 + j][nr];
        lp[j] = ls[kc4 + j][nr];
    }
    *(short4*)&hiT[(size_t)(n0 + nr) * K + k0 + kc4] = hv;
    *(short4*)&loT[(size_t)(n0 + nr) * K + k0 + kc4] = lv;
}

// -------------------- LayerNorm (fp32 out; optional index gather) --------------------
template<bool IDX>
__global__ __launch_bounds__(256) void ln_kernel(const float* __restrict__ x,
                                                 const float* __restrict__ gam,
                                                 const float* __restrict__ bet,
                                                 float* __restrict__ out,
                                                 const int* __restrict__ idx,
                                                 const int* __restrict__ cnt) {
    int wv = threadIdx.x >> 6, lane = threadIdx.x & 63;
    int p = (blockIdx.x << 2) | wv;
    if (IDX && p >= *cnt) return;
    int t = IDX ? idx[p] : p;
    const float* row = x + (size_t)t * DIM;
    int base = lane * 8;
    float4 v0 = *(const float4*)&row[base];
    float4 v1 = *(const float4*)&row[base + 4];
    float s = v0.x + v0.y + v0.z + v0.w + v1.x + v1.y + v1.z + v1.w;
#pragma unroll
    for (int o = 32; o; o >>= 1) s += __shfl_xor(s, o, 64);
    float mean = s * (1.0f / (float)DIM);
    float d0 = v0.x - mean, d1 = v0.y - mean, d2 = v0.z - mean, d3 = v0.w - mean;
    float d4 = v1.x - mean, d5 = v1.y - mean, d6 = v1.z - mean, d7 = v1.w - mean;
    float q = d0*d0 + d1*d1 + d2*d2 + d3*d3 + d4*d4 + d5*d5 + d6*d6 + d7*d7;
#pragma unroll
    for (int o = 32; o; o >>= 1) q += __shfl_xor(q, o, 64);
    float var = q * (1.0f / (float)DIM);
    float rs = 1.0f / sqrtf(var + 1e-5f);
    float4 g0 = *(const float4*)&gam[base];
    float4 g1 = *(const float4*)&gam[base + 4];
    float4 b0 = *(const float4*)&bet[base];
    float4 b1 = *(const float4*)&bet[base + 4];
    float4 o0, o1;
    o0.x = d0 * rs * g0.x + b0.x;  o0.y = d1 * rs * g0.y + b0.y;
    o0.z = d2 * rs * g0.z + b0.z;  o0.w = d3 * rs * g0.w + b0.w;
    o1.x = d4 * rs * g1.x + b1.x;  o1.y = d5 * rs * g1.y + b1.y;
    o1.z = d6 * rs * g1.z + b1.z;  o1.w = d7 * rs * g1.w + b1.w;
    float* orow = out + (size_t)p * DIM;
    *(float4*)&orow[base] = o0;
    *(float4*)&orow[base + 4] = o1;
}

// -------------------- LayerNorm -> bf16 hi/lo (dense, block 0) --------------------
__global__ __launch_bounds__(256) void ln_hilo(const float* __restrict__ x,
                                               const float* __restrict__ gam,
                                               const float* __restrict__ bet,
                                               short* __restrict__ ohi,
                                               short* __restrict__ olo) {
    int wv = threadIdx.x >> 6, lane = threadIdx.x & 63;
    int t = (blockIdx.x << 2) | wv;
    const float* row = x + (size_t)t * DIM;
    int base = lane * 8;
    float4 v0 = *(const float4*)&row[base];
    float4 v1 = *(const float4*)&row[base + 4];
    float s = v0.x + v0.y + v0.z + v0.w + v1.x + v1.y + v1.z + v1.w;
#pragma unroll
    for (int o = 32; o; o >>= 1) s += __shfl_xor(s, o, 64);
    float mean = s * (1.0f / (float)DIM);
    float d[8] = {v0.x - mean, v0.y - mean, v0.z - mean, v0.w - mean,
                  v1.x - mean, v1.y - mean, v1.z - mean, v1.w - mean};
    float q = 0.0f;
#pragma unroll
    for (int j = 0; j < 8; ++j) q += d[j] * d[j];
#pragma unroll
    for (int o = 32; o; o >>= 1) q += __shfl_xor(q, o, 64);
    float var = q * (1.0f / (float)DIM);
    float rs = 1.0f / sqrtf(var + 1e-5f);
    float g[8], bb[8];
    *(float4*)&g[0] = *(const float4*)&gam[base];
    *(float4*)&g[4] = *(const float4*)&gam[base + 4];
    *(float4*)&bb[0] = *(const float4*)&bet[base];
    *(float4*)&bb[4] = *(const float4*)&bet[base + 4];
    short8_t hv, lv;
#pragma unroll
    for (int j = 0; j < 8; ++j) {
        float val = d[j] * rs * g[j] + bb[j];
        unsigned short hb = f2bf_rn(val);
        float hf = __uint_as_float((unsigned)hb << 16);
        hv[j] = (short)hb;
        lv[j] = (short)f2bf_rn(val - hf);
    }
    *(short8_t*)&ohi[(size_t)t * DIM + base] = hv;
    *(short8_t*)&olo[(size_t)t * DIM + base] = lv;
}

// -------------------- split-bf16 MFMA GEMM (128x128, layers): C = A @ B^T --------------------
template<int EPI>
__global__ __launch_bounds__(256) void gemm_l_mfma(const short* __restrict__ Ah,
                                                   const short* __restrict__ Al,
                                                   const short* __restrict__ Bh,
                                                   const short* __restrict__ Bl,
                                                   float* __restrict__ Cf,
                                                   short* __restrict__ oHi,
                                                   short* __restrict__ oLo,
                                                   int N, int K) {
    __shared__ __align__(16) short sm[16384];
    short* sAh = sm;
    short* sAl = sm + 4096;
    short* sBh = sm + 8192;
    short* sBl = sm + 12288;
    const int tid = threadIdx.x;
    const int wv = tid >> 6, lane = tid & 63;
    const int m0 = blockIdx.x * 128;
    const int n0 = blockIdx.y * 128;
    const int wm = (wv & 1) * 64, wn = (wv >> 1) * 64;
    const int r16 = lane >> 2;
    const int gsw = ((lane & 3) ^ (r16 & 3)) << 3;
    const int fr = lane & 15;
    const int q = lane >> 4;

    f32x4 acc[4][4];
#pragma unroll
    for (int i = 0; i < 4; ++i)
#pragma unroll
        for (int j = 0; j < 4; ++j)
            acc[i][j] = (f32x4){0.0f, 0.0f, 0.0f, 0.0f};

    const int NKT = K >> 5;
    for (int kt = 0; kt < NKT; ++kt) {
        const int k0 = kt << 5;
        __syncthreads();
#pragma unroll
        for (int j = 0; j < 2; ++j) {
            const int rr = (wv << 5) + (j << 4);
            const int gr = rr + r16;
            const short* ga_h = Ah + (size_t)(m0 + gr) * K + k0 + gsw;
            const short* ga_l = Al + (size_t)(m0 + gr) * K + k0 + gsw;
            const short* gb_h = Bh + (size_t)(n0 + gr) * K + k0 + gsw;
            const short* gb_l = Bl + (size_t)(n0 + gr) * K + k0 + gsw;
            __builtin_amdgcn_global_load_lds((const __attribute__((address_space(1))) void*)ga_h,
                                             (__attribute__((address_space(3))) void*)(sAh + rr * 32), 16, 0, 0);
            __builtin_amdgcn_global_load_lds((const __attribute__((address_space(1))) void*)ga_l,
                                             (__attribute__((address_space(3))) void*)(sAl + rr * 32), 16, 0, 0);
            __builtin_amdgcn_global_load_lds((const __attribute__((address_space(1))) void*)gb_h,
                                             (__attribute__((address_space(3))) void*)(sBh + rr * 32), 16, 0, 0);
            __builtin_amdgcn_global_load_lds((const __attribute__((address_space(1))) void*)gb_l,
                                             (__attribute__((address_space(3))) void*)(sBl + rr * 32), 16, 0, 0);
        }
        __syncthreads();
        short8_t ah[4], al[4], bh[4], bl[4];
#pragma unroll
        for (int i = 0; i < 4; ++i) {
            const int ra = wm + i * 16 + fr;
            const int rb = wn + i * 16 + fr;
            const int swa = (q ^ (fr & 3)) << 3;
            ah[i] = *(const short8_t*)&sAh[ra * 32 + swa];
            al[i] = *(const short8_t*)&sAl[ra * 32 + swa];
            bh[i] = *(const short8_t*)&sBh[rb * 32 + swa];
            bl[i] = *(const short8_t*)&sBl[rb * 32 + swa];
        }
#pragma unroll
        for (int i = 0; i < 4; ++i)
#pragma unroll
            for (int j = 0; j < 4; ++j) {
                acc[i][j] = __builtin_amdgcn_mfma_f32_16x16x32_bf16(ah[i], bh[j], acc[i][j], 0, 0, 0);
                acc[i][j] = __builtin_amdgcn_mfma_f32_16x16x32_bf16(ah[i], bl[j], acc[i][j], 0, 0, 0);
                acc[i][j] = __builtin_amdgcn_mfma_f32_16x16x32_bf16(al[i], bh[j], acc[i][j], 0, 0, 0);
            }
    }
    const int row_base = (lane >> 4) << 2;
#pragma unroll
    for (int i = 0; i < 4; ++i)
#pragma unroll
        for (int j = 0; j < 4; ++j) {
            const int row = m0 + wm + i * 16 + row_base;
            const int col = n0 + wn + j * 16 + fr;
#pragma unroll
            for (int r = 0; r < 4; ++r) {
                float val = acc[i][j][r];
                if (EPI == 3) {
                    Cf[(size_t)(row + r) * N + col] = val;
                } else if (EPI == 2) {
                    Cf[(size_t)(row + r) * N + col] += val;
                } else {
                    if (EPI == 1) val = gelu_f(val);
                    unsigned short hb = f2bf_rn(val);
                    float hf = __uint_as_float((unsigned)hb << 16);
                    oHi[(size_t)(row + r) * N + col] = (short)hb;
                    oLo[(size_t)(row + r) * N + col] = (short)f2bf_rn(val - hf);
                }
            }
        }
}

// -------------------- 128x128 pipelined split-bf16 head GEMM, 2 blocks/CU --------------------
// Same counted-vmcnt / raw-barrier schedule as R5 (verified), but 64 KiB LDS so two
// blocks co-reside per CU: one block's C-write epilogue + prologue overlaps the
// sibling's MFMA. 256 threads = 4 waves (2x2 of 64x64).
__global__ __launch_bounds__(256, 2) void gemm_head_128(const short* __restrict__ Ah,
                                                        const short* __restrict__ Al,
                                                        const short* __restrict__ Bh,
                                                        const short* __restrict__ Bl,
                                                        float* __restrict__ C) {
    __shared__ __align__(16) short sm[32768];  // 64 KiB: 4 arrays x 2 buf x [128][32]
    const int tid = threadIdx.x;
    const int wv = tid >> 6, lane = tid & 63;
    const int wm = (wv & 1) * 64, wn = (wv >> 1) * 64;
    const int fr = lane & 15;
    const int swz = (((lane >> 4) ^ ((fr >> 1) & 3)) << 3);  // read-side granule swizzle
    // bijective XCD swizzle: 8000 WGs = 8 XCDs x 1000, m-fastest within chunk
    const int wg = blockIdx.x;
    const int sw = (wg & 7) * 1000 + (wg >> 3);
    const int m0 = (sw & 31) * 128;
    const int n0 = (sw >> 5) * 128;
    const int sub = lane >> 2;
    const int ggr = ((lane & 3) ^ ((lane >> 3) & 3)) << 3;   // pre-swizzled source granule

    const short* gA[2] = {Ah + (size_t)m0 * DIM, Al + (size_t)m0 * DIM};
    const short* gB[2] = {Bh + (size_t)n0 * DIM, Bl + (size_t)n0 * DIM};

    // per array per buf: [128][32] shorts = 4096; array stride 8192 (2 bufs)
#define STAGE_HEAD(bufi, kt)                                                              \
    {                                                                                     \
        const int k0s = (kt) << 5;                                                        \
        _Pragma("unroll")                                                                 \
        for (int arr = 0; arr < 4; ++arr) {                                               \
            const short* gsrc = (arr < 2 ? gA[arr] : gB[arr - 2]);                        \
            short* ldsb = sm + arr * 8192 + (bufi) * 4096;                                \
            _Pragma("unroll")                                                             \
            for (int r = 0; r < 2; ++r) {                                                 \
                const int rowb = wv * 32 + r * 16;                                        \
                const short* src = gsrc + (size_t)(rowb + sub) * DIM + k0s + ggr;         \
                short* dst = ldsb + rowb * 32;                                            \
                __builtin_amdgcn_global_load_lds(                                         \
                    (const __attribute__((address_space(1))) void*)src,                   \
                    (__attribute__((address_space(3))) void*)dst, 16, 0, 0);              \
            }                                                                             \
        }                                                                                 \
    }

    f32x4 acc[4][4];
#pragma unroll
    for (int i = 0; i < 4; ++i)
#pragma unroll
        for (int j = 0; j < 4; ++j)
            acc[i][j] = (f32x4){0.0f, 0.0f, 0.0f, 0.0f};

    STAGE_HEAD(0, 0)
    STAGE_HEAD(1, 1)

    const int NKT = DIM / 32;  // 16
    for (int t = 0; t < NKT; ++t) {
        if (t < NKT - 1) {
            asm volatile("s_waitcnt vmcnt(8)" ::: "memory");
        } else {
            asm volatile("s_waitcnt vmcnt(0)" ::: "memory");
        }
        __builtin_amdgcn_sched_barrier(0);
        __builtin_amdgcn_s_barrier();
        const int buf = t & 1;
        const short* pAh = sm + buf * 4096;
        const short* pAl = sm + 8192 + buf * 4096;
        const short* pBh = sm + 16384 + buf * 4096;
        const short* pBl = sm + 24576 + buf * 4096;
        __builtin_amdgcn_s_setprio(1);
        short8_t bh[4], bl[4];
#pragma unroll
        for (int j = 0; j < 4; ++j) {
            const int rb = wn + j * 16 + fr;
            bh[j] = *(const short8_t*)&pBh[rb * 32 + swz];
            bl[j] = *(const short8_t*)&pBl[rb * 32 + swz];
        }
#pragma unroll
        for (int i = 0; i < 4; ++i) {
            const int ra = wm + i * 16 + fr;
            short8_t ah = *(const short8_t*)&pAh[ra * 32 + swz];
            short8_t al = *(const short8_t*)&pAl[ra * 32 + swz];
#pragma unroll
            for (int j = 0; j < 4; ++j)
                acc[i][j] = __builtin_amdgcn_mfma_f32_16x16x32_bf16(ah, bh[j], acc[i][j], 0, 0, 0);
#pragma unroll
            for (int j = 0; j < 4; ++j)
                acc[i][j] = __builtin_amdgcn_mfma_f32_16x16x32_bf16(ah, bl[j], acc[i][j], 0, 0, 0);
#pragma unroll
            for (int j = 0; j < 4; ++j)
                acc[i][j] = __builtin_amdgcn_mfma_f32_16x16x32_bf16(al, bh[j], acc[i][j], 0, 0, 0);
        }
        __builtin_amdgcn_s_setprio(0);
        asm volatile("s_waitcnt lgkmcnt(0)" ::: "memory");
        __builtin_amdgcn_sched_barrier(0);
        __builtin_amdgcn_s_barrier();
        if (t + 2 < NKT) {
            STAGE_HEAD(buf, t + 2)
        }
    }
#undef STAGE_HEAD

    const int row_base = (lane >> 4) << 2;
#pragma unroll
    for (int i = 0; i < 4; ++i)
#pragma unroll
        for (int j = 0; j < 4; ++j) {
            const int row = m0 + wm + i * 16 + row_base;
            const int col = n0 + wn + j * 16 + fr;
#pragma unroll
            for (int r = 0; r < 4; ++r)
                C[(size_t)(row + r) * NVOCAB + col] = acc[i][j][r];
        }
}

// -------------------- fp32 tiled GEMM (blocks 1-2 compact path) --------------------
template<bool ADD, bool GELU, bool GUARD, bool SCAT>
__global__ __launch_bounds__(256) void gemm_nn(const float* __restrict__ A,
                                               const float* __restrict__ B,
                                               float* __restrict__ C,
                                               int M, int N, int K,
                                               const int* __restrict__ idx,
                                               const int* __restrict__ cnt) {
    const int m0 = blockIdx.y * 64, n0 = blockIdx.x * 64;
    int c = GUARD ? *cnt : M;
    if (GUARD && m0 >= c) return;
    __shared__ float As[16][68];
    __shared__ float Bs[16][68];
    const int tid = threadIdx.x;
    const int am = tid >> 2, ak = (tid & 3) << 2;
    const int bk = tid >> 4, bn = (tid & 15) << 2;
    const int tn = tid & 15, tm = tid >> 4;
    int ar = m0 + am;
    if (GUARD) ar = ar < c ? ar : c - 1;
    float acc[4][4] = {};
    for (int k0 = 0; k0 < K; k0 += 16) {
        float4 a4 = *(const float4*)&A[(size_t)ar * K + k0 + ak];
        float4 b4 = *(const float4*)&B[(size_t)(k0 + bk) * N + n0 + bn];
        __syncthreads();
        As[ak + 0][am] = a4.x;
        As[ak + 1][am] = a4.y;
        As[ak + 2][am] = a4.z;
        As[ak + 3][am] = a4.w;
        *(float4*)&Bs[bk][bn] = b4;
        __syncthreads();
#pragma unroll
        for (int kk = 0; kk < 16; ++kk) {
            float4 av = *(const float4*)&As[kk][tm << 2];
            float4 bv = *(const float4*)&Bs[kk][tn << 2];
            float a[4] = {av.x, av.y, av.z, av.w};
            float b[4] = {bv.x, bv.y, bv.z, bv.w};
#pragma unroll
            for (int i = 0; i < 4; ++i)
#pragma unroll
                for (int j = 0; j < 4; ++j)
                    acc[i][j] = fmaf(a[i], b[j], acc[i][j]);
        }
    }
#pragma unroll
    for (int i = 0; i < 4; ++i) {
        int p = m0 + (tm << 2) + i;
        if (GUARD && p >= c) continue;
        int r = SCAT ? idx[p] : p;
        float* cp = &C[(size_t)r * N + n0 + (tn << 2)];
        float rr[4] = {acc[i][0], acc[i][1], acc[i][2], acc[i][3]};
        if (GELU) {
#pragma unroll
            for (int j = 0; j < 4; ++j) rr[j] = gelu_f(rr[j]);
        }
        if (ADD) {
            float4 cc = *(const float4*)cp;
            rr[0] += cc.x; rr[1] += cc.y; rr[2] += cc.z; rr[3] += cc.w;
        }
        float4 rv = {rr[0], rr[1], rr[2], rr[3]};
        *(float4*)cp = rv;
    }
}

// -------------------- fp32 head GEMM (fallback / compacted blocks 1-2) --------------------
template<bool IDX>
__global__ __launch_bounds__(256) void gemm_nt_head(const float* __restrict__ A,
                                                    const float* __restrict__ Bt,
                                                    float* __restrict__ C,
                                                    const int* __restrict__ idx,
                                                    const int* __restrict__ cnt,
                                                    int N, int K) {
    const int m0 = blockIdx.y * 64, n0 = blockIdx.x * 64;
    int c = IDX ? *cnt : TT;
    if (IDX && m0 >= c) return;
    __shared__ float As[16][68];
    __shared__ float Bs[16][68];
    const int tid = threadIdx.x;
    const int am = tid >> 2, ak = (tid & 3) << 2;
    const int tn = tid & 15, tm = tid >> 4;
    int ar = m0 + am;
    if (IDX) ar = idx[ar < c ? ar : c - 1];
    float acc[4][4] = {};
    for (int k0 = 0; k0 < K; k0 += 16) {
        float4 a4 = *(const float4*)&A[(size_t)ar * K + k0 + ak];
        float4 b4 = *(const float4*)&Bt[(size_t)(n0 + am) * K + k0 + ak];
        __syncthreads();
        As[ak + 0][am] = a4.x;
        As[ak + 1][am] = a4.y;
        As[ak + 2][am] = a4.z;
        As[ak + 3][am] = a4.w;
        Bs[ak + 0][am] = b4.x;
        Bs[ak + 1][am] = b4.y;
        Bs[ak + 2][am] = b4.z;
        Bs[ak + 3][am] = b4.w;
        __syncthreads();
#pragma unroll
        for (int kk = 0; kk < 16; ++kk) {
            float4 av = *(const float4*)&As[kk][tm << 2];
            float4 bv = *(const float4*)&Bs[kk][tn << 2];
            float a[4] = {av.x, av.y, av.z, av.w};
            float b[4] = {bv.x, bv.y, bv.z, bv.w};
#pragma unroll
            for (int i = 0; i < 4; ++i)
#pragma unroll
                for (int j = 0; j < 4; ++j)
                    acc[i][j] = fmaf(a[i], b[j], acc[i][j]);
        }
    }
#pragma unroll
    for (int i = 0; i < 4; ++i) {
        int p = m0 + (tm << 2) + i;
        if (IDX && p >= c) continue;
        int r = IDX ? idx[p] : p;
        float4 rv = {acc[i][0], acc[i][1], acc[i][2], acc[i][3]};
        *(float4*)&C[(size_t)r * N + n0 + (tn << 2)] = rv;
    }
}

// -------------------- confidence + exit decision --------------------
template<bool IDX>
__global__ __launch_bounds__(256) void conf_exit(const float* __restrict__ out,
                                                 int* __restrict__ flags,
                                                 const int* __restrict__ idx,
                                                 const int* __restrict__ cnt,
                                                 float thr) {
    int t;
    if (IDX) {
        if (blockIdx.x >= *cnt) return;
        t = idx[blockIdx.x];
    } else {
        t = blockIdx.x;
        if (flags[t] == 0) return;
    }
    const float* row = out + (size_t)t * NVOCAB;
    float m = -INFINITY, s = 0.0f;
    for (int i = threadIdx.x; i < NVOCAB; i += 256) {
        float x = row[i];
        if (x > m) {
            s = s * expf(m - x) + 1.0f;
            m = x;
        } else {
            s += expf(x - m);
        }
    }
    __shared__ float ms[256], ss[256];
    ms[threadIdx.x] = m;
    ss[threadIdx.x] = s;
    __syncthreads();
    for (int st = 128; st; st >>= 1) {
        if (threadIdx.x < st) {
            float m1 = ms[threadIdx.x], s1 = ss[threadIdx.x];
            float m2 = ms[threadIdx.x + st], s2 = ss[threadIdx.x + st];
            float mm = fmaxf(m1, m2);
            ss[threadIdx.x] = s1 * expf(m1 - mm) + s2 * expf(m2 - mm);
            ms[threadIdx.x] = mm;
        }
        __syncthreads();
    }
    if (threadIdx.x == 0) {
        float conf = 1.0f / ss[0];
        if (conf > thr) flags[t] = 0;
    }
}

// -------------------- ordered compaction of active tokens (single block) --------------------
__global__ __launch_bounds__(256) void compact_kernel(const int* __restrict__ flags,
                                                      int* __restrict__ idx,
                                                      int* __restrict__ cnt) {
    __shared__ int wsum[4];
    __shared__ int base;
    if (threadIdx.x == 0) base = 0;
    int lane = threadIdx.x & 63, wv = threadIdx.x >> 6;
    for (int chunk = 0; chunk < TT; chunk += 256) {
        __syncthreads();
        int t = chunk + threadIdx.x;
        int f = flags[t];
        unsigned long long b = __ballot(f != 0);
        if (lane == 0) wsum[wv] = __popcll(b);
        __syncthreads();
        int off = base;
        for (int w = 0; w < wv; ++w) off += wsum[w];
        off += __popcll(b & ((1ull << lane) - 1));
        if (f) idx[off] = t;
        __syncthreads();
        if (threadIdx.x == 0) base += wsum[0] + wsum[1] + wsum[2] + wsum[3];
    }
    __syncthreads();
    if (threadIdx.x == 0) *cnt = base;
}

extern "C" void kernel_launch(void* const* d_in, const int* in_sizes, int n_in,
                              void* d_out, int out_size, void* d_ws, size_t ws_size,
                              hipStream_t stream) {
    const int* x = (const int*)d_in[0];
    const float* emb = (const float*)d_in[1];
    const float* head = (const float*)d_in[2];
    const float* Wv = (const float*)d_in[3];
    const float* Wo = (const float*)d_in[4];
    const float* W1 = (const float*)d_in[5];
    const float* W2 = (const float*)d_in[6];
    const float* ln1s = (const float*)d_in[7];
    const float* ln1b = (const float*)d_in[8];
    const float* ln2s = (const float*)d_in[9];
    const float* ln2b = (const float*)d_in[10];
    float* out = (float*)d_out;
    float* ws = (float*)d_ws;

    float* h  = ws;                      // TT*DIM fp32
    float* hn = ws + 2097152;            // TT*DIM
    float* tA = ws + 4194304;            // TT*DIM
    float* tF = ws + 6291456;            // TT*FFN
    short* hnHi = (short*)hn;
    short* hnLo = hnHi + TT * DIM;
    short* tAHi = (short*)tA;
    short* tALo = tAHi + TT * DIM;
    short* tFHi = (short*)tF;
    short* tFLo = tFHi + TT * FFN;
    int* flags = (int*)(ws + 14680064);  // TT
    int* idxl  = flags + TT;             // TT
    int* cntp  = flags + 2 * TT;         // 1
    short* hHi    = (short*)(ws + 14700000);
    short* hLo    = (short*)(ws + 15748576);
    short* headHi = (short*)(ws + 16797152);
    short* headLo = (short*)(ws + 24989152);
    short* wT     = (short*)(ws + 33181152);  // 2 layers x 5242880 shorts
    const size_t LSTRIDE = 5242880;
    const size_t NEED_T2 = (size_t)33181152 * 4;
    const size_t NEED_T1 = (size_t)38424032 * 4;
    const int tier = ws_size >= NEED_T1 ? 1 : (ws_size >= NEED_T2 ? 2 : 3);

    gather_kernel<<<TT, 128, 0, stream>>>(x, emb, h, flags);

    const float THR[3] = {3.5e-05f, 4.0e-05f, 1.0f};
    const dim3 gDD(DIM / 64, TT / 64), gDF(FFN / 64, TT / 64), gHead(NVOCAB / 64, TT / 64);

    // ---------- block 0: dense ----------
    if (tier == 1) {
        for (int l = 0; l < 2; ++l) {
            short* wb = wT + (size_t)l * LSTRIDE;
            cvt_w_t<<<dim3(DIM / 32, DIM / 32), 256, 0, stream>>>(Wv + (size_t)l * DIM * DIM, wb, wb + 262144, DIM, DIM);
            cvt_w_t<<<dim3(DIM / 32, DIM / 32), 256, 0, stream>>>(Wo + (size_t)l * DIM * DIM, wb + 524288, wb + 786432, DIM, DIM);
            cvt_w_t<<<dim3(FFN / 32, DIM / 32), 256, 0, stream>>>(W1 + (size_t)l * DIM * FFN, wb + 1048576, wb + 2097152, DIM, FFN);
            cvt_w_t<<<dim3(DIM / 32, FFN / 32), 256, 0, stream>>>(W2 + (size_t)l * FFN * DIM, wb + 3145728, wb + 4194304, FFN, DIM);
        }
        for (int l = 0; l < 2; ++l) {
            short* wb = wT + (size_t)l * LSTRIDE;
            ln_hilo<<<TT / 4, 256, 0, stream>>>(h, ln1s + l * DIM, ln1b + l * DIM, hnHi, hnLo);
            gemm_l_mfma<0><<<dim3(TT / 128, DIM / 128), 256, 0, stream>>>(hnHi, hnLo, wb, wb + 262144, nullptr, tAHi, tALo, DIM, DIM);
            gemm_l_mfma<2><<<dim3(TT / 128, DIM / 128), 256, 0, stream>>>(tAHi, tALo, wb + 524288, wb + 786432, h, nullptr, nullptr, DIM, DIM);
            ln_hilo<<<TT / 4, 256, 0, stream>>>(h, ln2s + l * DIM, ln2b + l * DIM, hnHi, hnLo);
            gemm_l_mfma<1><<<dim3(TT / 128, FFN / 128), 256, 0, stream>>>(hnHi, hnLo, wb + 1048576, wb + 2097152, nullptr, tFHi, tFLo, FFN, DIM);
            gemm_l_mfma<2><<<dim3(TT / 128, DIM / 128), 256, 0, stream>>>(tFHi, tFLo, wb + 3145728, wb + 4194304, h, nullptr, nullptr, DIM, FFN);
        }
    } else {
        for (int l = 0; l < 2; ++l) {
            ln_kernel<false><<<TT / 4, 256, 0, stream>>>(h, ln1s + l * DIM, ln1b + l * DIM, hn, nullptr, nullptr);
            gemm_nn<false, false, false, false><<<gDD, 256, 0, stream>>>(hn, Wv + (size_t)l * DIM * DIM, tA, TT, DIM, DIM, nullptr, nullptr);
            gemm_nn<true, false, false, false><<<gDD, 256, 0, stream>>>(tA, Wo + (size_t)l * DIM * DIM, h, TT, DIM, DIM, nullptr, nullptr);
            ln_kernel<false><<<TT / 4, 256, 0, stream>>>(h, ln2s + l * DIM, ln2b + l * DIM, hn, nullptr, nullptr);
            gemm_nn<false, true, false, false><<<gDF, 256, 0, stream>>>(hn, W1 + (size_t)l * DIM * FFN, tF, TT, FFN, DIM, nullptr, nullptr);
            gemm_nn<true, false, false, false><<<gDD, 256, 0, stream>>>(tF, W2 + (size_t)l * FFN * DIM, h, TT, DIM, FFN, nullptr, nullptr);
        }
    }
    if (tier <= 2) {
        cvt_hilo<<<(TT * DIM / 4 + 255) / 256, 256, 0, stream>>>(h, hHi, hLo, TT * DIM / 4);
        cvt_hilo<<<(NVOCAB * DIM / 4 + 255) / 256, 256, 0, stream>>>(head, headHi, headLo, NVOCAB * DIM / 4);
        gemm_head_128<<<8000, 256, 0, stream>>>(hHi, hLo, headHi, headLo, out);
    } else {
        gemm_nt_head<false><<<gHead, 256, 0, stream>>>(h, head, out, nullptr, nullptr, NVOCAB, DIM);
    }
    conf_exit<false><<<TT, 256, 0, stream>>>(out, flags, nullptr, nullptr, THR[0]);
    compact_kernel<<<1, 256, 0, stream>>>(flags, idxl, cntp);

    // ---------- blocks 1,2: compacted active rows (fp32 path; ~empty on this input) ----------
    for (int b = 1; b < 3; ++b) {
        for (int li = 0; li < 2; ++li) {
            int l = b * 2 + li;
            ln_kernel<true><<<TT / 4, 256, 0, stream>>>(h, ln1s + l * DIM, ln1b + l * DIM, hn, idxl, cntp);
            gemm_nn<false, false, true, false><<<gDD, 256, 0, stream>>>(hn, Wv + (size_t)l * DIM * DIM, tA, TT, DIM, DIM, idxl, cntp);
            gemm_nn<true, false, true, true><<<gDD, 256, 0, stream>>>(tA, Wo + (size_t)l * DIM * DIM, h, TT, DIM, DIM, idxl, cntp);
            ln_kernel<true><<<TT / 4, 256, 0, stream>>>(h, ln2s + l * DIM, ln2b + l * DIM, hn, idxl, cntp);
            gemm_nn<false, true, true, false><<<gDF, 256, 0, stream>>>(hn, W1 + (size_t)l * DIM * FFN, tF, TT, FFN, DIM, idxl, cntp);
            gemm_nn<true, false, true, true><<<gDD, 256, 0, stream>>>(tF, W2 + (size_t)l * FFN * DIM, h, TT, DIM, FFN, idxl, cntp);
        }
        gemm_nt_head<true><<<gHead, 256, 0, stream>>>(h, head, out, idxl, cntp, NVOCAB, DIM);
        if (b == 1) {
            conf_exit<true><<<TT, 256, 0, stream>>>(out, flags, idxl, cntp, THR[1]);
            compact_kernel<<<1, 256, 0, stream>>>(flags, idxl, cntp);
        }
    }
}

// Round 7
// 1055.774 us; speedup vs baseline: 1.1028x; 1.1028x over previous
//
#include <hip/hip_runtime.h>
#include <hip/hip_bf16.h>
#include <math.h>

#define TT 4096
#define DIM 512
#define FFN 2048
#define NVOCAB 32000
#define NT 250

typedef __attribute__((ext_vector_type(8))) short short8_t;
typedef __attribute__((ext_vector_type(4))) float f32x4;

__device__ __forceinline__ float gelu_f(float x) {
    float x3 = x * x * x;
    float u = 0.7978845608028654f * (x + 0.044715f * x3);
    return 0.5f * x * (1.0f + tanhf(u));
}

__device__ __forceinline__ unsigned short f2bf_rn(float f) {
    unsigned u = __float_as_uint(f);
    u += 0x7FFFu + ((u >> 16) & 1u);
    return (unsigned short)(u >> 16);
}

// -------------------- embedding gather + flag init --------------------
__global__ __launch_bounds__(128) void gather_kernel(const int* __restrict__ x,
                                                     const float* __restrict__ emb,
                                                     float* __restrict__ h,
                                                     int* __restrict__ flags) {
    int t = blockIdx.x;
    int idx = x[t];
    const float4 v = *(const float4*)&emb[(size_t)idx * DIM + threadIdx.x * 4];
    *(float4*)&h[(size_t)t * DIM + threadIdx.x * 4] = v;
    if (threadIdx.x == 0) flags[t] = 1;
}

// -------------------- fp32 -> bf16 hi/lo split (flat) --------------------
__global__ __launch_bounds__(256) void cvt_hilo(const float* __restrict__ src,
                                                short* __restrict__ hi,
                                                short* __restrict__ lo, int n4) {
    int i = blockIdx.x * 256 + threadIdx.x;
    if (i >= n4) return;
    float4 v = *(const float4*)&src[(size_t)i * 4];
    float f[4] = {v.x, v.y, v.z, v.w};
    short4 hv, lv;
    short* hp = &hv.x;
    short* lp = &lv.x;
#pragma unroll
    for (int j = 0; j < 4; ++j) {
        unsigned short hb = f2bf_rn(f[j]);
        float hf = __uint_as_float((unsigned)hb << 16);
        unsigned short lb = f2bf_rn(f[j] - hf);
        hp[j] = (short)hb;
        lp[j] = (short)lb;
    }
    *(short4*)&hi[(size_t)i * 4] = hv;
    *(short4*)&lo[(size_t)i * 4] = lv;
}

// -------------------- fp32 W (K,N) -> bf16 hi/lo transposed (N,K) --------------------
__global__ __launch_bounds__(256) void cvt_w_t(const float* __restrict__ W,
                                               short* __restrict__ hiT,
                                               short* __restrict__ loT,
                                               int K, int N) {
    __shared__ short hs[32][36];
    __shared__ short ls[32][36];
    const int n0 = blockIdx.x * 32, k0 = blockIdx.y * 32;
    const int r = threadIdx.x >> 3, c4 = (threadIdx.x & 7) << 2;
    float4 v = *(const float4*)&W[(size_t)(k0 + r) * N + n0 + c4];
    float f[4] = {v.x, v.y, v.z, v.w};
#pragma unroll
    for (int j = 0; j < 4; ++j) {
        unsigned short hb = f2bf_rn(f[j]);
        float hf = __uint_as_float((unsigned)hb << 16);
        unsigned short lb = f2bf_rn(f[j] - hf);
        hs[r][c4 + j] = (short)hb;
        ls[r][c4 + j] = (short)lb;
    }
    __syncthreads();
    const int nr = threadIdx.x >> 3, kc4 = (threadIdx.x & 7) << 2;
    short4 hv, lv;
    short* hp = &hv.x;
    short* lp = &lv.x;
#pragma unroll
    for (int j = 0; j < 4; ++j) {
        hp[j] = hs[kc4 + j][nr];
        lp[j] = ls[kc4 + j][nr];
    }
    *(short4*)&hiT[(size_t)(n0 + nr) * K + k0 + kc4] = hv;
    *(short4*)&loT[(size_t)(n0 + nr) * K + k0 + kc4] = lv;
}

// -------------------- LayerNorm (fp32 out; optional index gather) --------------------
template<bool IDX>
__global__ __launch_bounds__(256) void ln_kernel(const float* __restrict__ x,
                                                 const float* __restrict__ gam,
                                                 const float* __restrict__ bet,
                                                 float* __restrict__ out,
                                                 const int* __restrict__ idx,
                                                 const int* __restrict__ cnt) {
    int wv = threadIdx.x >> 6, lane = threadIdx.x & 63;
    int p = (blockIdx.x << 2) | wv;
    if (IDX && p >= *cnt) return;
    int t = IDX ? idx[p] : p;
    const float* row = x + (size_t)t * DIM;
    int base = lane * 8;
    float4 v0 = *(const float4*)&row[base];
    float4 v1 = *(const float4*)&row[base + 4];
    float s = v0.x + v0.y + v0.z + v0.w + v1.x + v1.y + v1.z + v1.w;
#pragma unroll
    for (int o = 32; o; o >>= 1) s += __shfl_xor(s, o, 64);
    float mean = s * (1.0f / (float)DIM);
    float d0 = v0.x - mean, d1 = v0.y - mean, d2 = v0.z - mean, d3 = v0.w - mean;
    float d4 = v1.x - mean, d5 = v1.y - mean, d6 = v1.z - mean, d7 = v1.w - mean;
    float q = d0*d0 + d1*d1 + d2*d2 + d3*d3 + d4*d4 + d5*d5 + d6*d6 + d7*d7;
#pragma unroll
    for (int o = 32; o; o >>= 1) q += __shfl_xor(q, o, 64);
    float var = q * (1.0f / (float)DIM);
    float rs = 1.0f / sqrtf(var + 1e-5f);
    float4 g0 = *(const float4*)&gam[base];
    float4 g1 = *(const float4*)&gam[base + 4];
    float4 b0 = *(const float4*)&bet[base];
    float4 b1 = *(const float4*)&bet[base + 4];
    float4 o0, o1;
    o0.x = d0 * rs * g0.x + b0.x;  o0.y = d1 * rs * g0.y + b0.y;
    o0.z = d2 * rs * g0.z + b0.z;  o0.w = d3 * rs * g0.w + b0.w;
    o1.x = d4 * rs * g1.x + b1.x;  o1.y = d5 * rs * g1.y + b1.y;
    o1.z = d6 * rs * g1.z + b1.z;  o1.w = d7 * rs * g1.w + b1.w;
    float* orow = out + (size_t)p * DIM;
    *(float4*)&orow[base] = o0;
    *(float4*)&orow[base + 4] = o1;
}

// -------------------- LayerNorm -> bf16 hi/lo (dense, block 0) --------------------
__global__ __launch_bounds__(256) void ln_hilo(const float* __restrict__ x,
                                               const float* __restrict__ gam,
                                               const float* __restrict__ bet,
                                               short* __restrict__ ohi,
                                               short* __restrict__ olo) {
    int wv = threadIdx.x >> 6, lane = threadIdx.x & 63;
    int t = (blockIdx.x << 2) | wv;
    const float* row = x + (size_t)t * DIM;
    int base = lane * 8;
    float4 v0 = *(const float4*)&row[base];
    float4 v1 = *(const float4*)&row[base + 4];
    float s = v0.x + v0.y + v0.z + v0.w + v1.x + v1.y + v1.z + v1.w;
#pragma unroll
    for (int o = 32; o; o >>= 1) s += __shfl_xor(s, o, 64);
    float mean = s * (1.0f / (float)DIM);
    float d[8] = {v0.x - mean, v0.y - mean, v0.z - mean, v0.w - mean,
                  v1.x - mean, v1.y - mean, v1.z - mean, v1.w - mean};
    float q = 0.0f;
#pragma unroll
    for (int j = 0; j < 8; ++j) q += d[j] * d[j];
#pragma unroll
    for (int o = 32; o; o >>= 1) q += __shfl_xor(q, o, 64);
    float var = q * (1.0f / (float)DIM);
    float rs = 1.0f / sqrtf(var + 1e-5f);
    float g[8], bb[8];
    *(float4*)&g[0] = *(const float4*)&gam[base];
    *(float4*)&g[4] = *(const float4*)&gam[base + 4];
    *(float4*)&bb[0] = *(const float4*)&bet[base];
    *(float4*)&bb[4] = *(const float4*)&bet[base + 4];
    short8_t hv, lv;
#pragma unroll
    for (int j = 0; j < 8; ++j) {
        float val = d[j] * rs * g[j] + bb[j];
        unsigned short hb = f2bf_rn(val);
        float hf = __uint_as_float((unsigned)hb << 16);
        hv[j] = (short)hb;
        lv[j] = (short)f2bf_rn(val - hf);
    }
    *(short8_t*)&ohi[(size_t)t * DIM + base] = hv;
    *(short8_t*)&olo[(size_t)t * DIM + base] = lv;
}

// -------------------- split-bf16 MFMA GEMM (128x128): C(M,N) = A(M,K) @ B(N,K)^T -----
// EPI: 0 = store hi/lo bf16; 1 = gelu + store hi/lo; 2 = residual add into Cf;
//      3 = plain fp32 store; 4 = residual add into Cf AND store hi/lo of the sum.
template<int EPI>
__global__ __launch_bounds__(256) void gemm_l_mfma(const short* __restrict__ Ah,
                                                   const short* __restrict__ Al,
                                                   const short* __restrict__ Bh,
                                                   const short* __restrict__ Bl,
                                                   float* __restrict__ Cf,
                                                   short* __restrict__ oHi,
                                                   short* __restrict__ oLo,
                                                   int N, int K) {
    __shared__ __align__(16) short sm[16384];
    short* sAh = sm;
    short* sAl = sm + 4096;
    short* sBh = sm + 8192;
    short* sBl = sm + 12288;
    const int tid = threadIdx.x;
    const int wv = tid >> 6, lane = tid & 63;
    const int m0 = blockIdx.x * 128;
    const int n0 = blockIdx.y * 128;
    const int wm = (wv & 1) * 64, wn = (wv >> 1) * 64;
    const int r16 = lane >> 2;
    const int gsw = ((lane & 3) ^ (r16 & 3)) << 3;
    const int fr = lane & 15;
    const int q = lane >> 4;

    f32x4 acc[4][4];
#pragma unroll
    for (int i = 0; i < 4; ++i)
#pragma unroll
        for (int j = 0; j < 4; ++j)
            acc[i][j] = (f32x4){0.0f, 0.0f, 0.0f, 0.0f};

    const int NKT = K >> 5;
    for (int kt = 0; kt < NKT; ++kt) {
        const int k0 = kt << 5;
        __syncthreads();
#pragma unroll
        for (int j = 0; j < 2; ++j) {
            const int rr = (wv << 5) + (j << 4);
            const int gr = rr + r16;
            const short* ga_h = Ah + (size_t)(m0 + gr) * K + k0 + gsw;
            const short* ga_l = Al + (size_t)(m0 + gr) * K + k0 + gsw;
            const short* gb_h = Bh + (size_t)(n0 + gr) * K + k0 + gsw;
            const short* gb_l = Bl + (size_t)(n0 + gr) * K + k0 + gsw;
            __builtin_amdgcn_global_load_lds((const __attribute__((address_space(1))) void*)ga_h,
                                             (__attribute__((address_space(3))) void*)(sAh + rr * 32), 16, 0, 0);
            __builtin_amdgcn_global_load_lds((const __attribute__((address_space(1))) void*)ga_l,
                                             (__attribute__((address_space(3))) void*)(sAl + rr * 32), 16, 0, 0);
            __builtin_amdgcn_global_load_lds((const __attribute__((address_space(1))) void*)gb_h,
                                             (__attribute__((address_space(3))) void*)(sBh + rr * 32), 16, 0, 0);
            __builtin_amdgcn_global_load_lds((const __attribute__((address_space(1))) void*)gb_l,
                                             (__attribute__((address_space(3))) void*)(sBl + rr * 32), 16, 0, 0);
        }
        __syncthreads();
        short8_t ah[4], al[4], bh[4], bl[4];
#pragma unroll
        for (int i = 0; i < 4; ++i) {
            const int ra = wm + i * 16 + fr;
            const int rb = wn + i * 16 + fr;
            const int swa = (q ^ (fr & 3)) << 3;
            ah[i] = *(const short8_t*)&sAh[ra * 32 + swa];
            al[i] = *(const short8_t*)&sAl[ra * 32 + swa];
            bh[i] = *(const short8_t*)&sBh[rb * 32 + swa];
            bl[i] = *(const short8_t*)&sBl[rb * 32 + swa];
        }
#pragma unroll
        for (int i = 0; i < 4; ++i)
#pragma unroll
            for (int j = 0; j < 4; ++j) {
                acc[i][j] = __builtin_amdgcn_mfma_f32_16x16x32_bf16(ah[i], bh[j], acc[i][j], 0, 0, 0);
                acc[i][j] = __builtin_amdgcn_mfma_f32_16x16x32_bf16(ah[i], bl[j], acc[i][j], 0, 0, 0);
                acc[i][j] = __builtin_amdgcn_mfma_f32_16x16x32_bf16(al[i], bh[j], acc[i][j], 0, 0, 0);
            }
    }
    const int row_base = (lane >> 4) << 2;
#pragma unroll
    for (int i = 0; i < 4; ++i)
#pragma unroll
        for (int j = 0; j < 4; ++j) {
            const int row = m0 + wm + i * 16 + row_base;
            const int col = n0 + wn + j * 16 + fr;
#pragma unroll
            for (int r = 0; r < 4; ++r) {
                float val = acc[i][j][r];
                if (EPI == 3) {
                    Cf[(size_t)(row + r) * N + col] = val;
                } else if (EPI == 2) {
                    Cf[(size_t)(row + r) * N + col] += val;
                } else if (EPI == 4) {
                    float* cp = &Cf[(size_t)(row + r) * N + col];
                    float nv = *cp + val;
                    *cp = nv;
                    unsigned short hb = f2bf_rn(nv);
                    float hf = __uint_as_float((unsigned)hb << 16);
                    oHi[(size_t)(row + r) * N + col] = (short)hb;
                    oLo[(size_t)(row + r) * N + col] = (short)f2bf_rn(nv - hf);
                } else {
                    if (EPI == 1) val = gelu_f(val);
                    unsigned short hb = f2bf_rn(val);
                    float hf = __uint_as_float((unsigned)hb << 16);
                    oHi[(size_t)(row + r) * N + col] = (short)hb;
                    oLo[(size_t)(row + r) * N + col] = (short)f2bf_rn(val - hf);
                }
            }
        }
}

// -------------------- head GEMM + fused confidence partials --------------------
// R4-proven 128x128 structure (978 TF-eff), plus per-row (max, sumexp) partials of the
// 128-col tile written to pm/ps (token x n-tile) for the cheap conf_reduce pass.
__global__ __launch_bounds__(256) void gemm_head_fused(const short* __restrict__ Ah,
                                                       const short* __restrict__ Al,
                                                       const short* __restrict__ Bh,
                                                       const short* __restrict__ Bl,
                                                       float* __restrict__ C,
                                                       float* __restrict__ pm,
                                                       float* __restrict__ ps) {
    __shared__ __align__(16) short sm[16384];
    short* sAh = sm;
    short* sAl = sm + 4096;
    short* sBh = sm + 8192;
    short* sBl = sm + 12288;
    const int tid = threadIdx.x;
    const int wv = tid >> 6, lane = tid & 63;
    const int m0 = blockIdx.x * 128;
    const int n0 = blockIdx.y * 128;
    const int nt = blockIdx.y;
    const int wm = (wv & 1) * 64, wn = (wv >> 1) * 64;
    const int r16 = lane >> 2;
    const int gsw = ((lane & 3) ^ (r16 & 3)) << 3;
    const int fr = lane & 15;
    const int q = lane >> 4;

    f32x4 acc[4][4];
#pragma unroll
    for (int i = 0; i < 4; ++i)
#pragma unroll
        for (int j = 0; j < 4; ++j)
            acc[i][j] = (f32x4){0.0f, 0.0f, 0.0f, 0.0f};

    const int NKT = DIM >> 5;
    for (int kt = 0; kt < NKT; ++kt) {
        const int k0 = kt << 5;
        __syncthreads();
#pragma unroll
        for (int j = 0; j < 2; ++j) {
            const int rr = (wv << 5) + (j << 4);
            const int gr = rr + r16;
            const short* ga_h = Ah + (size_t)(m0 + gr) * DIM + k0 + gsw;
            const short* ga_l = Al + (size_t)(m0 + gr) * DIM + k0 + gsw;
            const short* gb_h = Bh + (size_t)(n0 + gr) * DIM + k0 + gsw;
            const short* gb_l = Bl + (size_t)(n0 + gr) * DIM + k0 + gsw;
            __builtin_amdgcn_global_load_lds((const __attribute__((address_space(1))) void*)ga_h,
                                             (__attribute__((address_space(3))) void*)(sAh + rr * 32), 16, 0, 0);
            __builtin_amdgcn_global_load_lds((const __attribute__((address_space(1))) void*)ga_l,
                                             (__attribute__((address_space(3))) void*)(sAl + rr * 32), 16, 0, 0);
            __builtin_amdgcn_global_load_lds((const __attribute__((address_space(1))) void*)gb_h,
                                             (__attribute__((address_space(3))) void*)(sBh + rr * 32), 16, 0, 0);
            __builtin_amdgcn_global_load_lds((const __attribute__((address_space(1))) void*)gb_l,
                                             (__attribute__((address_space(3))) void*)(sBl + rr * 32), 16, 0, 0);
        }
        __syncthreads();
        short8_t ah[4], al[4], bh[4], bl[4];
#pragma unroll
        for (int i = 0; i < 4; ++i) {
            const int ra = wm + i * 16 + fr;
            const int rb = wn + i * 16 + fr;
            const int swa = (q ^ (fr & 3)) << 3;
            ah[i] = *(const short8_t*)&sAh[ra * 32 + swa];
            al[i] = *(const short8_t*)&sAl[ra * 32 + swa];
            bh[i] = *(const short8_t*)&sBh[rb * 32 + swa];
            bl[i] = *(const short8_t*)&sBl[rb * 32 + swa];
        }
#pragma unroll
        for (int i = 0; i < 4; ++i)
#pragma unroll
            for (int j = 0; j < 4; ++j) {
                acc[i][j] = __builtin_amdgcn_mfma_f32_16x16x32_bf16(ah[i], bh[j], acc[i][j], 0, 0, 0);
                acc[i][j] = __builtin_amdgcn_mfma_f32_16x16x32_bf16(ah[i], bl[j], acc[i][j], 0, 0, 0);
                acc[i][j] = __builtin_amdgcn_mfma_f32_16x16x32_bf16(al[i], bh[j], acc[i][j], 0, 0, 0);
            }
    }
    const int hi = lane >> 4;
    const int row_base = hi << 2;
#pragma unroll
    for (int i = 0; i < 4; ++i)
#pragma unroll
        for (int j = 0; j < 4; ++j) {
            const int row = m0 + wm + i * 16 + row_base;
            const int col = n0 + wn + j * 16 + fr;
#pragma unroll
            for (int r = 0; r < 4; ++r)
                C[(size_t)(row + r) * NVOCAB + col] = acc[i][j][r];
        }
    // fused confidence partials: per-row max & sumexp over this WG's 128 cols
    __syncthreads();
    float2* confS = (float2*)sm;  // [128][2] halves
#pragma unroll
    for (int i = 0; i < 4; ++i)
#pragma unroll
        for (int r = 0; r < 4; ++r) {
            float v0 = acc[i][0][r], v1 = acc[i][1][r];
            float v2 = acc[i][2][r], v3 = acc[i][3][r];
            float mg = fmaxf(fmaxf(v0, v1), fmaxf(v2, v3));
#pragma unroll
            for (int o = 1; o < 16; o <<= 1) mg = fmaxf(mg, __shfl_xor(mg, o, 64));
            float sg = __expf(v0 - mg) + __expf(v1 - mg) + __expf(v2 - mg) + __expf(v3 - mg);
#pragma unroll
            for (int o = 1; o < 16; o <<= 1) sg += __shfl_xor(sg, o, 64);
            if (fr == 0)
                confS[(wm + i * 16 + hi * 4 + r) * 2 + (wn >> 6)] = make_float2(mg, sg);
        }
    __syncthreads();
    if (tid < 128) {
        float2 a = confS[tid * 2 + 0];
        float2 b = confS[tid * 2 + 1];
        float mm = fmaxf(a.x, b.x);
        float ss = a.y * __expf(a.x - mm) + b.y * __expf(b.x - mm);
        pm[(size_t)(m0 + tid) * NT + nt] = mm;
        ps[(size_t)(m0 + tid) * NT + nt] = ss;
    }
}

// -------------------- conf reduce over head partials (one wave per token) ---------
__global__ __launch_bounds__(256) void conf_reduce(const float* __restrict__ pm,
                                                   const float* __restrict__ ps,
                                                   int* __restrict__ flags, float thr) {
    int wv = threadIdx.x >> 6, lane = threadIdx.x & 63;
    int t = blockIdx.x * 4 + wv;
    float m = -INFINITY, s = 0.0f;
    for (int k = lane; k < NT; k += 64) {
        float me = pm[(size_t)t * NT + k];
        float se = ps[(size_t)t * NT + k];
        float mm = fmaxf(m, me);
        s = s * __expf(m - mm) + se * __expf(me - mm);
        m = mm;
    }
#pragma unroll
    for (int o = 1; o < 64; o <<= 1) {
        float mo = __shfl_xor(m, o, 64);
        float so = __shfl_xor(s, o, 64);
        float mm = fmaxf(m, mo);
        s = s * __expf(m - mm) + so * __expf(mo - mm);
        m = mm;
    }
    if (lane == 0) {
        float conf = 1.0f / s;
        if (conf > thr) flags[t] = 0;
    }
}

// -------------------- fp32 tiled GEMM (blocks 1-2 compact path) --------------------
template<bool ADD, bool GELU, bool GUARD, bool SCAT>
__global__ __launch_bounds__(256) void gemm_nn(const float* __restrict__ A,
                                               const float* __restrict__ B,
                                               float* __restrict__ C,
                                               int M, int N, int K,
                                               const int* __restrict__ idx,
                                               const int* __restrict__ cnt) {
    const int m0 = blockIdx.y * 64, n0 = blockIdx.x * 64;
    int c = GUARD ? *cnt : M;
    if (GUARD && m0 >= c) return;
    __shared__ float As[16][68];
    __shared__ float Bs[16][68];
    const int tid = threadIdx.x;
    const int am = tid >> 2, ak = (tid & 3) << 2;
    const int bk = tid >> 4, bn = (tid & 15) << 2;
    const int tn = tid & 15, tm = tid >> 4;
    int ar = m0 + am;
    if (GUARD) ar = ar < c ? ar : c - 1;
    float acc[4][4] = {};
    for (int k0 = 0; k0 < K; k0 += 16) {
        float4 a4 = *(const float4*)&A[(size_t)ar * K + k0 + ak];
        float4 b4 = *(const float4*)&B[(size_t)(k0 + bk) * N + n0 + bn];
        __syncthreads();
        As[ak + 0][am] = a4.x;
        As[ak + 1][am] = a4.y;
        As[ak + 2][am] = a4.z;
        As[ak + 3][am] = a4.w;
        *(float4*)&Bs[bk][bn] = b4;
        __syncthreads();
#pragma unroll
        for (int kk = 0; kk < 16; ++kk) {
            float4 av = *(const float4*)&As[kk][tm << 2];
            float4 bv = *(const float4*)&Bs[kk][tn << 2];
            float a[4] = {av.x, av.y, av.z, av.w};
            float b[4] = {bv.x, bv.y, bv.z, bv.w};
#pragma unroll
            for (int i = 0; i < 4; ++i)
#pragma unroll
                for (int j = 0; j < 4; ++j)
                    acc[i][j] = fmaf(a[i], b[j], acc[i][j]);
        }
    }
#pragma unroll
    for (int i = 0; i < 4; ++i) {
        int p = m0 + (tm << 2) + i;
        if (GUARD && p >= c) continue;
        int r = SCAT ? idx[p] : p;
        float* cp = &C[(size_t)r * N + n0 + (tn << 2)];
        float rr[4] = {acc[i][0], acc[i][1], acc[i][2], acc[i][3]};
        if (GELU) {
#pragma unroll
            for (int j = 0; j < 4; ++j) rr[j] = gelu_f(rr[j]);
        }
        if (ADD) {
            float4 cc = *(const float4*)cp;
            rr[0] += cc.x; rr[1] += cc.y; rr[2] += cc.z; rr[3] += cc.w;
        }
        float4 rv = {rr[0], rr[1], rr[2], rr[3]};
        *(float4*)cp = rv;
    }
}

// -------------------- fp32 head GEMM (fallback / compacted blocks 1-2) --------------------
template<bool IDX>
__global__ __launch_bounds__(256) void gemm_nt_head(const float* __restrict__ A,
                                                    const float* __restrict__ Bt,
                                                    float* __restrict__ C,
                                                    const int* __restrict__ idx,
                                                    const int* __restrict__ cnt,
                                                    int N, int K) {
    const int m0 = blockIdx.y * 64, n0 = blockIdx.x * 64;
    int c = IDX ? *cnt : TT;
    if (IDX && m0 >= c) return;
    __shared__ float As[16][68];
    __shared__ float Bs[16][68];
    const int tid = threadIdx.x;
    const int am = tid >> 2, ak = (tid & 3) << 2;
    const int tn = tid & 15, tm = tid >> 4;
    int ar = m0 + am;
    if (IDX) ar = idx[ar < c ? ar : c - 1];
    float acc[4][4] = {};
    for (int k0 = 0; k0 < K; k0 += 16) {
        float4 a4 = *(const float4*)&A[(size_t)ar * K + k0 + ak];
        float4 b4 = *(const float4*)&Bt[(size_t)(n0 + am) * K + k0 + ak];
        __syncthreads();
        As[ak + 0][am] = a4.x;
        As[ak + 1][am] = a4.y;
        As[ak + 2][am] = a4.z;
        As[ak + 3][am] = a4.w;
        Bs[ak + 0][am] = b4.x;
        Bs[ak + 1][am] = b4.y;
        Bs[ak + 2][am] = b4.z;
        Bs[ak + 3][am] = b4.w;
        __syncthreads();
#pragma unroll
        for (int kk = 0; kk < 16; ++kk) {
            float4 av = *(const float4*)&As[kk][tm << 2];
            float4 bv = *(const float4*)&Bs[kk][tn << 2];
            float a[4] = {av.x, av.y, av.z, av.w};
            float b[4] = {bv.x, bv.y, bv.z, bv.w};
#pragma unroll
            for (int i = 0; i < 4; ++i)
#pragma unroll
                for (int j = 0; j < 4; ++j)
                    acc[i][j] = fmaf(a[i], b[j], acc[i][j]);
        }
    }
#pragma unroll
    for (int i = 0; i < 4; ++i) {
        int p = m0 + (tm << 2) + i;
        if (IDX && p >= c) continue;
        int r = IDX ? idx[p] : p;
        float4 rv = {acc[i][0], acc[i][1], acc[i][2], acc[i][3]};
        *(float4*)&C[(size_t)r * N + n0 + (tn << 2)] = rv;
    }
}

// -------------------- confidence + exit (full-row re-read; tiers 2-3 and block 1) ----
template<bool IDX>
__global__ __launch_bounds__(256) void conf_exit(const float* __restrict__ out,
                                                 int* __restrict__ flags,
                                                 const int* __restrict__ idx,
                                                 const int* __restrict__ cnt,
                                                 float thr) {
    int t;
    if (IDX) {
        if (blockIdx.x >= *cnt) return;
        t = idx[blockIdx.x];
    } else {
        t = blockIdx.x;
        if (flags[t] == 0) return;
    }
    const float* row = out + (size_t)t * NVOCAB;
    float m = -INFINITY, s = 0.0f;
    for (int i = threadIdx.x; i < NVOCAB; i += 256) {
        float x = row[i];
        if (x > m) {
            s = s * expf(m - x) + 1.0f;
        } else {
            s += expf(x - m);
        }
        m = fmaxf(m, x);
    }
    __shared__ float ms[256], ss[256];
    ms[threadIdx.x] = m;
    ss[threadIdx.x] = s;
    __syncthreads();
    for (int st = 128; st; st >>= 1) {
        if (threadIdx.x < st) {
            float m1 = ms[threadIdx.x], s1 = ss[threadIdx.x];
            float m2 = ms[threadIdx.x + st], s2 = ss[threadIdx.x + st];
            float mm = fmaxf(m1, m2);
            ss[threadIdx.x] = s1 * expf(m1 - mm) + s2 * expf(m2 - mm);
            ms[threadIdx.x] = mm;
        }
        __syncthreads();
    }
    if (threadIdx.x == 0) {
        float conf = 1.0f / ss[0];
        if (conf > thr) flags[t] = 0;
    }
}

// -------------------- ordered compaction of active tokens (single block) --------------------
__global__ __launch_bounds__(256) void compact_kernel(const int* __restrict__ flags,
                                                      int* __restrict__ idx,
                                                      int* __restrict__ cnt) {
    __shared__ int wsum[4];
    __shared__ int base;
    if (threadIdx.x == 0) base = 0;
    int lane = threadIdx.x & 63, wv = threadIdx.x >> 6;
    for (int chunk = 0; chunk < TT; chunk += 256) {
        __syncthreads();
        int t = chunk + threadIdx.x;
        int f = flags[t];
        unsigned long long b = __ballot(f != 0);
        if (lane == 0) wsum[wv] = __popcll(b);
        __syncthreads();
        int off = base;
        for (int w = 0; w < wv; ++w) off += wsum[w];
        off += __popcll(b & ((1ull << lane) - 1));
        if (f) idx[off] = t;
        __syncthreads();
        if (threadIdx.x == 0) base += wsum[0] + wsum[1] + wsum[2] + wsum[3];
    }
    __syncthreads();
    if (threadIdx.x == 0) *cnt = base;
}

extern "C" void kernel_launch(void* const* d_in, const int* in_sizes, int n_in,
                              void* d_out, int out_size, void* d_ws, size_t ws_size,
                              hipStream_t stream) {
    const int* x = (const int*)d_in[0];
    const float* emb = (const float*)d_in[1];
    const float* head = (const float*)d_in[2];
    const float* Wv = (const float*)d_in[3];
    const float* Wo = (const float*)d_in[4];
    const float* W1 = (const float*)d_in[5];
    const float* W2 = (const float*)d_in[6];
    const float* ln1s = (const float*)d_in[7];
    const float* ln1b = (const float*)d_in[8];
    const float* ln2s = (const float*)d_in[9];
    const float* ln2b = (const float*)d_in[10];
    float* out = (float*)d_out;
    float* ws = (float*)d_ws;

    float* h  = ws;                      // TT*DIM fp32
    float* hn = ws + 2097152;            // TT*DIM
    float* tA = ws + 4194304;            // TT*DIM (scratch: WvFlat hi/lo during setup)
    float* tF = ws + 6291456;            // TT*FFN
    short* hnHi = (short*)hn;
    short* hnLo = hnHi + TT * DIM;
    short* tAHi = (short*)tA;
    short* tALo = tAHi + TT * DIM;
    short* tFHi = (short*)tF;
    short* tFLo = tFHi + TT * FFN;
    int* flags = (int*)(ws + 14680064);  // TT
    int* idxl  = flags + TT;             // TT
    int* cntp  = flags + 2 * TT;         // 1
    short* hHi    = (short*)(ws + 14700000);
    short* hLo    = (short*)(ws + 15748576);
    short* headHi = (short*)(ws + 16797152);
    short* headLo = (short*)(ws + 24989152);
    short* wT     = (short*)(ws + 33181152);  // 2 layers x 5242880 shorts
    float* pm = ws + 38424032;           // TT*NT
    float* ps = ws + 39448032;           // TT*NT
    const size_t LSTRIDE = 5242880;
    const size_t NEED_T2 = (size_t)33181152 * 4;
    const size_t NEED_T1 = (size_t)40472032 * 4;
    const int tier = ws_size >= NEED_T1 ? 1 : (ws_size >= NEED_T2 ? 2 : 3);

    gather_kernel<<<TT, 128, 0, stream>>>(x, emb, h, flags);

    const float THR[3] = {3.5e-05f, 4.0e-05f, 1.0f};
    const dim3 gDD(DIM / 64, TT / 64), gDF(FFN / 64, TT / 64), gHead(NVOCAB / 64, TT / 64);

    // ---------- block 0: dense ----------
    if (tier == 1) {
        // weight prep: WoT, W1T, W2T transpose-splits; W_voT = WoT @ WvFlat (MFMA)
        for (int l = 0; l < 2; ++l) {
            short* wb = wT + (size_t)l * LSTRIDE;
            cvt_hilo<<<(DIM * DIM / 4 + 255) / 256, 256, 0, stream>>>(Wv + (size_t)l * DIM * DIM, tAHi, tALo, DIM * DIM / 4);
            cvt_w_t<<<dim3(DIM / 32, DIM / 32), 256, 0, stream>>>(Wo + (size_t)l * DIM * DIM, wb + 524288, wb + 786432, DIM, DIM);
            // W_voT[n][k] = sum_j WoT[n][j] * Wv[k][j]
            gemm_l_mfma<0><<<dim3(DIM / 128, DIM / 128), 256, 0, stream>>>(
                wb + 524288, wb + 786432, tAHi, tALo, nullptr, wb, wb + 262144, DIM, DIM);
            cvt_w_t<<<dim3(FFN / 32, DIM / 32), 256, 0, stream>>>(W1 + (size_t)l * DIM * FFN, wb + 1048576, wb + 2097152, DIM, FFN);
            cvt_w_t<<<dim3(DIM / 32, FFN / 32), 256, 0, stream>>>(W2 + (size_t)l * FFN * DIM, wb + 3145728, wb + 4194304, FFN, DIM);
        }
        for (int l = 0; l < 2; ++l) {
            short* wb = wT + (size_t)l * LSTRIDE;
            ln_hilo<<<TT / 4, 256, 0, stream>>>(h, ln1s + l * DIM, ln1b + l * DIM, hnHi, hnLo);
            gemm_l_mfma<2><<<dim3(TT / 128, DIM / 128), 256, 0, stream>>>(hnHi, hnLo, wb, wb + 262144, h, nullptr, nullptr, DIM, DIM);
            ln_hilo<<<TT / 4, 256, 0, stream>>>(h, ln2s + l * DIM, ln2b + l * DIM, hnHi, hnLo);
            gemm_l_mfma<1><<<dim3(TT / 128, FFN / 128), 256, 0, stream>>>(hnHi, hnLo, wb + 1048576, wb + 2097152, nullptr, tFHi, tFLo, FFN, DIM);
            if (l == 1) {
                gemm_l_mfma<4><<<dim3(TT / 128, DIM / 128), 256, 0, stream>>>(tFHi, tFLo, wb + 3145728, wb + 4194304, h, hHi, hLo, DIM, FFN);
            } else {
                gemm_l_mfma<2><<<dim3(TT / 128, DIM / 128), 256, 0, stream>>>(tFHi, tFLo, wb + 3145728, wb + 4194304, h, nullptr, nullptr, DIM, FFN);
            }
        }
        cvt_hilo<<<(NVOCAB * DIM / 4 + 255) / 256, 256, 0, stream>>>(head, headHi, headLo, NVOCAB * DIM / 4);
        gemm_head_fused<<<dim3(TT / 128, NVOCAB / 128), 256, 0, stream>>>(hHi, hLo, headHi, headLo, out, pm, ps);
        conf_reduce<<<TT / 4, 256, 0, stream>>>(pm, ps, flags, THR[0]);
    } else {
        for (int l = 0; l < 2; ++l) {
            ln_kernel<false><<<TT / 4, 256, 0, stream>>>(h, ln1s + l * DIM, ln1b + l * DIM, hn, nullptr, nullptr);
            gemm_nn<false, false, false, false><<<gDD, 256, 0, stream>>>(hn, Wv + (size_t)l * DIM * DIM, tA, TT, DIM, DIM, nullptr, nullptr);
            gemm_nn<true, false, false, false><<<gDD, 256, 0, stream>>>(tA, Wo + (size_t)l * DIM * DIM, h, TT, DIM, DIM, nullptr, nullptr);
            ln_kernel<false><<<TT / 4, 256, 0, stream>>>(h, ln2s + l * DIM, ln2b + l * DIM, hn, nullptr, nullptr);
            gemm_nn<false, true, false, false><<<gDF, 256, 0, stream>>>(hn, W1 + (size_t)l * DIM * FFN, tF, TT, FFN, DIM, nullptr, nullptr);
            gemm_nn<true, false, false, false><<<gDD, 256, 0, stream>>>(tF, W2 + (size_t)l * FFN * DIM, h, TT, DIM, FFN, nullptr, nullptr);
        }
        if (tier == 2) {
            cvt_hilo<<<(TT * DIM / 4 + 255) / 256, 256, 0, stream>>>(h, hHi, hLo, TT * DIM / 4);
            cvt_hilo<<<(NVOCAB * DIM / 4 + 255) / 256, 256, 0, stream>>>(head, headHi, headLo, NVOCAB * DIM / 4);
            gemm_l_mfma<3><<<dim3(TT / 128, NVOCAB / 128), 256, 0, stream>>>(hHi, hLo, headHi, headLo, out, nullptr, nullptr, NVOCAB, DIM);
        } else {
            gemm_nt_head<false><<<gHead, 256, 0, stream>>>(h, head, out, nullptr, nullptr, NVOCAB, DIM);
        }
        conf_exit<false><<<TT, 256, 0, stream>>>(out, flags, nullptr, nullptr, THR[0]);
    }
    compact_kernel<<<1, 256, 0, stream>>>(flags, idxl, cntp);

    // ---------- blocks 1,2: compacted active rows (fp32 path; ~empty on this input) ----------
    for (int b = 1; b < 3; ++b) {
        for (int li = 0; li < 2; ++li) {
            int l = b * 2 + li;
            ln_kernel<true><<<TT / 4, 256, 0, stream>>>(h, ln1s + l * DIM, ln1b + l * DIM, hn, idxl, cntp);
            gemm_nn<false, false, true, false><<<gDD, 256, 0, stream>>>(hn, Wv + (size_t)l * DIM * DIM, tA, TT, DIM, DIM, idxl, cntp);
            gemm_nn<true, false, true, true><<<gDD, 256, 0, stream>>>(tA, Wo + (size_t)l * DIM * DIM, h, TT, DIM, DIM, idxl, cntp);
            ln_kernel<true><<<TT / 4, 256, 0, stream>>>(h, ln2s + l * DIM, ln2b + l * DIM, hn, idxl, cntp);
            gemm_nn<false, true, true, false><<<gDF, 256, 0, stream>>>(hn, W1 + (size_t)l * DIM * FFN, tF, TT, FFN, DIM, idxl, cntp);
            gemm_nn<true, false, true, true><<<gDD, 256, 0, stream>>>(tF, W2 + (size_t)l * FFN * DIM, h, TT, DIM, FFN, idxl, cntp);
        }
        gemm_nt_head<true><<<gHead, 256, 0, stream>>>(h, head, out, idxl, cntp, NVOCAB, DIM);
        if (b == 1) {
            conf_exit<true><<<TT, 256, 0, stream>>>(out, flags, idxl, cntp, THR[1]);
            compact_kernel<<<1, 256, 0, stream>>>(flags, idxl, cntp);
        }
    }
}